// Round 21
// baseline (104.573 us; speedup 1.0000x reference)
//
#include <hip/hip_runtime.h>
#include <cstdint>
#include <cstddef>

#define B_ 256
#define IW_ 3072
#define L_ 8
#define NN_ 7
#define FCIN_ 16384
#define OUTW_ 10
#define ICST 72            // ushorts per (row,col) cell: 64 ic + 8 pad
#define YPLANE (324 * ICST)   // 23328 us = 46.66 KB per buffer

typedef short short8 __attribute__((ext_vector_type(8)));
typedef float f32x4 __attribute__((ext_vector_type(4)));

__device__ __forceinline__ ushort f2bf(float x) {
    uint u = __float_as_uint(x);
    return (ushort)((u + 0x7fffu + ((u >> 16) & 1u)) >> 16);
}
__device__ __forceinline__ float bf2f(ushort b) { return __uint_as_float(((uint)b) << 16); }

// ---------- merged prep: [0,64) w1 repack | [64,1216) w2 repack | [1216,1472) mixture ----------
__global__ __launch_bounds__(256) void k_prep(const float* __restrict__ w1, ushort* __restrict__ w1fr,
                                              const float* __restrict__ w2, ushort* __restrict__ w2r,
                                              const float* __restrict__ x, const float* __restrict__ nw,
                                              const float* __restrict__ nb, float* __restrict__ mix) {
    int blk = blockIdx.x;
    if (blk < 64) {
        // conv1 weights -> frag-linear single RTN plane: [l8][mt4][lane64][j8]
        int i = blk * 256 + threadIdx.x;
        int j    = i & 7;
        int lane = (i >> 3) & 63;
        int mt   = (i >> 9) & 3;
        int l    = i >> 11;
        int fr = lane & 15, fq = lane >> 4;
        int oc = mt * 16 + fr;
        int k = fq * 8 + j;
        float w = (k < 27) ? w1[(size_t)(l * 64 + oc) * 27 + k] : 0.f;
        w1fr[i] = f2bf(w);
        return;
    }
    if (blk < 1216) {
        // conv2 weights -> [l8][icc2][tap9][mt4][lane64][j8], single RTN bf16 plane
        int i = (blk - 64) * 256 + threadIdx.x;
        int j     = i & 7;
        int lane  = (i >> 3) & 63;
        int mt    = (i >> 9) & 3;
        int tap   = (i >> 11) % 9;
        int icc   = (i / 18432) & 1;
        int l     = i / 36864;
        int fr = lane & 15, fq = lane >> 4;
        int oc = mt * 16 + fr;
        int ic = icc * 32 + fq * 8 + j;
        float w = w2[(((size_t)l * 64 + oc) * 64 + ic) * 9 + tap];
        w2r[i] = f2bf(w);
        return;
    }
    // mixture
    __shared__ float red[4 * NN_];
    __shared__ float bes[NN_];
    int b = blk - 1216, tid = threadIdx.x;
    const float* xb = x + (size_t)b * IW_;
    float p[NN_];
#pragma unroll
    for (int n = 0; n < NN_; ++n) p[n] = 0.f;
    for (int i = tid; i < IW_; i += 256) {
        float xv = xb[i];
#pragma unroll
        for (int n = 0; n < NN_; ++n) p[n] = fmaf(xv, nw[n * IW_ + i], p[n]);
    }
#pragma unroll
    for (int n = 0; n < NN_; ++n) {
        float v = p[n];
        for (int off = 32; off > 0; off >>= 1) v += __shfl_xor(v, off);
        if ((tid & 63) == 0) red[(tid >> 6) * NN_ + n] = v;
    }
    __syncthreads();
    if (tid < NN_) {
        float s = red[tid] + red[NN_ + tid] + red[2 * NN_ + tid] + red[3 * NN_ + tid] + nb[tid];
        bes[tid] = 1.f / (1.f + expf(-s));
    }
    __syncthreads();
    if (tid < L_) {
        int leaf = tid;
        float b0 = bes[0];
        float t0 = ((leaf >> 2) & 1) ? b0 : 1.f - b0;
        float b1v = bes[1 + ((leaf >> 2) & 1)];
        float t1 = ((leaf >> 1) & 1) ? b1v : 1.f - b1v;
        float b2v = bes[3 + ((leaf >> 1) & 3)];
        float t2 = (leaf & 1) ? b2v : 1.f - b2v;
        mix[b * L_ + leaf] = t0 * t1 * t2;
    }
}

// ---------- fully-fused conv1/conv2/fc: 1024 thr, full-leaf dbuf steps, fc from LDS ----------
// block = sample (grid 256 = 1/CU), 16 waves = 4 waves/SIMD. 8 leaf-steps:
//   conv1(l+1) -> ybuf[(l+1)&1]  ||  conv2(l) <- ybuf[l&1] (A-frags from global/L1) -> barrier.
// Epilogue: oacc -> LDS out1 tile (64KB, fits after leaf loop) -> each thread reduces
// e = tid + k*1024 against ORIGINAL-layout fcw (256B coalesced wave-loads) -> wave+LDS
// reduce -> out[b][10]. No out1 in HBM, no k_fc kernel.
__global__ __launch_bounds__(1024, 1) void k_fused(const float* __restrict__ x,
                                                   const ushort* __restrict__ w1fr,
                                                   const float* __restrict__ cb1,
                                                   const ushort* __restrict__ w2r,
                                                   const float* __restrict__ cb2, const float* __restrict__ mixw,
                                                   const float* __restrict__ fcw, const float* __restrict__ fcb,
                                                   float* __restrict__ out) {
    __shared__ __align__(16) ushort smem[2 * YPLANE];   // ybuf0 | ybuf1 = 93.3 KB
    float* xpad = (float*)smem;                          // prologue-only alias (13.9 KB)

    int tid = threadIdx.x;
    int b = blockIdx.x;
    int lane = tid & 63, wid = tid >> 6;                 // wid 0..15
    int fr = lane & 15, fq = lane >> 4;
    int mt = wid >> 2, ng = wid & 3;                     // conv2: mtile mt, rows {4ng..4ng+3}

    // ---- prologue: xpad zero + fill ----
    for (int i = tid; i < 3 * 34 * 34; i += 1024) xpad[i] = 0.f;
    __syncthreads();
    for (int i = tid; i < 3072; i += 1024) {
        int ch = i >> 10, rr = (i >> 5) & 31, cc = i & 31;
        xpad[(ch * 34 + rr + 1) * 34 + cc + 1] = x[(size_t)b * IW_ + i];
    }
    __syncthreads();

    // ---- leaf-invariant conv1 im2col B-frags: wave owns pooled row wid ----
    short8 Bh[4];
#pragma unroll
    for (int i = 0; i < 4; ++i) {
        int subrow = i >> 1;
        int parity = i & 1;
        int prow = wid * 2 + subrow;          // 0..31
        int pcol = 2 * fr + parity;           // 0..31
#pragma unroll
        for (int j = 0; j < 8; ++j) {
            int k = fq * 8 + j;               // k = ic*9 + tap
            float xv = 0.f;
            if (k < 27) {
                int ic = k / 9;
                int tap = k - ic * 9;
                int dr = tap / 3, dc = tap - dr * 3;
                xv = xpad[(ic * 34 + prow + dr) * 34 + (pcol + dc)];
            }
            Bh[i][j] = (short)f2bf(xv);
        }
    }
    __syncthreads();
    {   // zero BOTH y planes (borders stay zero forever)
        uint4 z; z.x = z.y = z.z = z.w = 0u;
        for (int i = tid; i < (2 * YPLANE) / 8; i += 1024) ((uint4*)smem)[i] = z;
    }
    __syncthreads();

    f32x4 acc[4], oacc[4];
#pragma unroll
    for (int rl = 0; rl < 4; ++rl) { acc[rl] = (f32x4)0.f; oacc[rl] = (f32x4)0.f; }

    // conv1(l): all 64 chans of leaf l for pooled row wid -> ybuf[l&1]
    auto CONV1 = [&](int l) {
        ushort* yt = smem + (size_t)(l & 1) * YPLANE;
#pragma unroll
        for (int mtg = 0; mtg < 4; ++mtg) {
            short8 ah = *(const short8*)(w1fr + ((size_t)(l * 4 + mtg) * 64 + lane) * 8);
            f32x4 a1[4];
#pragma unroll
            for (int i = 0; i < 4; ++i) {
                f32x4 t = (f32x4)0.f;
                t = __builtin_amdgcn_mfma_f32_16x16x32_bf16(ah, Bh[i], t, 0, 0, 0);
                a1[i] = t;
            }
            float4 bias4 = *(const float4*)(cb1 + l * 64 + mtg * 16 + fq * 4);
            float bb[4] = {bias4.x, bias4.y, bias4.z, bias4.w};
            ushort hb[4];
#pragma unroll
            for (int j2 = 0; j2 < 4; ++j2) {
                float m0 = fmaxf(fmaxf(a1[0][j2], a1[1][j2]), fmaxf(a1[2][j2], a1[3][j2]));
                float v = fmaxf(m0 + bb[j2], 0.f);
                hb[j2] = f2bf(v);
            }
            int off = ((wid + 1) * 18 + (fr + 1)) * ICST + mtg * 16 + fq * 4;
            uint2 H;
            H.x = (uint)hb[0] | ((uint)hb[1] << 16);
            H.y = (uint)hb[2] | ((uint)hb[3] << 16);
            *(uint2*)&yt[off] = H;
        }
    };

    // conv2(l): reads ybuf[l&1], full K=64 (2 icc); A-frags from global (L1/L2-broadcast)
    auto CONV2 = [&](int l) {
        const ushort* yt = smem + (size_t)(l & 1) * YPLANE;
#pragma unroll
        for (int dc = 0; dc < 3; ++dc) {
#pragma unroll
            for (int icc = 0; icc < 2; ++icc) {
                const ushort* wbase = w2r + (size_t)(l * 2 + icc) * 18432;
                short8 Ah[3];
#pragma unroll
                for (int dr = 0; dr < 3; ++dr) {
                    int tap = dr * 3 + dc;
                    Ah[dr] = *(const short8*)(wbase + ((size_t)(tap * 4 + mt) * 64 + lane) * 8);
                }
#pragma unroll
                for (int rr = 0; rr < 6; ++rr) {
                    int off = ((4 * ng + rr) * 18 + (fr + dc)) * ICST + icc * 32 + fq * 8;
                    short8 bh = *(const short8*)(yt + off);
#pragma unroll
                    for (int dr = 0; dr < 3; ++dr) {
                        int rl = rr - dr;
                        if (rl >= 0 && rl < 4) {
                            acc[rl] = __builtin_amdgcn_mfma_f32_16x16x32_bf16(Ah[dr], bh, acc[rl], 0, 0, 0);
                        }
                    }
                }
            }
        }
        // leaf epilogue: bias + relu + mixture accumulate
        float mx = mixw[(size_t)b * 8 + l];
#pragma unroll
        for (int j = 0; j < 4; ++j) {
            float bias = cb2[l * 64 + mt * 16 + fq * 4 + j];
#pragma unroll
            for (int rl = 0; rl < 4; ++rl) {
                float v = fmaxf(acc[rl][j] + bias, 0.f);
                oacc[rl][j] = fmaf(mx, v, oacc[rl][j]);
                acc[rl][j] = 0.f;
            }
        }
    };

    // ---- software pipeline: conv1(l+1) || conv2(l), one barrier per leaf ----
    CONV1(0);
    __syncthreads();
    for (int l = 0; l < 8; ++l) {
        if (l < 7) CONV1(l + 1);
        CONV2(l);
        __syncthreads();
    }

    // ---- fc epilogue: oacc -> LDS out1 tile, then coalesced fcw reduce ----
    float* ldsOut = (float*)smem;          // 16384 floats = 64 KB (fits in 93.3)
    float* sred   = (float*)smem + FCIN_;  // 160 floats after the tile
#pragma unroll
    for (int rl = 0; rl < 4; ++rl)
#pragma unroll
        for (int j = 0; j < 4; ++j) {
            int oc = mt * 16 + fq * 4 + j;
            int pos = (4 * ng + rl) * 16 + fr;
            ldsOut[oc * 256 + pos] = oacc[rl][j];
        }
    __syncthreads();
    float pj[OUTW_];
#pragma unroll
    for (int j = 0; j < OUTW_; ++j) pj[j] = 0.f;
#pragma unroll
    for (int k = 0; k < 16; ++k) {
        float yv = ldsOut[k * 1024 + tid];
#pragma unroll
        for (int jj = 0; jj < OUTW_; ++jj)
            pj[jj] = fmaf(yv, fcw[(size_t)jj * FCIN_ + k * 1024 + tid], pj[jj]);
    }
#pragma unroll
    for (int jj = 0; jj < OUTW_; ++jj) {
        float v = pj[jj];
        for (int off = 32; off > 0; off >>= 1) v += __shfl_xor(v, off);
        if (lane == 0) sred[wid * OUTW_ + jj] = v;
    }
    __syncthreads();
    if (tid < OUTW_) {
        float s = fcb[tid];
#pragma unroll
        for (int w = 0; w < 16; ++w) s += sred[w * OUTW_ + tid];
        out[(size_t)b * OUTW_ + tid] = s;
    }
}

extern "C" void kernel_launch(void* const* d_in, const int* in_sizes, int n_in,
                              void* d_out, int out_size, void* d_ws, size_t ws_size,
                              hipStream_t stream) {
    const float* x   = (const float*)d_in[0];
    const float* nw  = (const float*)d_in[1];
    const float* nb  = (const float*)d_in[2];
    const float* w1  = (const float*)d_in[3];
    const float* cb1 = (const float*)d_in[4];
    const float* w2  = (const float*)d_in[5];
    const float* cb2 = (const float*)d_in[6];
    const float* fcw = (const float*)d_in[7];
    const float* fcb = (const float*)d_in[8];
    float* out = (float*)d_out;

    float*  ws   = (float*)d_ws;
    float*  mix  = ws;                        // 2048 f
    ushort* w1fr = (ushort*)(mix + 2048);     // 16384 us (single RTN plane)
    ushort* w2r  = w1fr + 16384;              // 294912 us ([l][icc][tap][mt][lane][j8] single plane)
    // fixed bytes: 2048*4 + 16384*2 + 294912*2 = 630784 (< ws_size)

    k_prep<<<1472, 256, 0, stream>>>(w1, w1fr, w2, w2r, x, nw, nb, mix);
    k_fused<<<B_, 1024, 0, stream>>>(x, w1fr, cb1, w2r, cb2, mix, fcw, fcb, out);
}

// Round 22
// 65.262 us; speedup vs baseline: 1.6024x; 1.6024x over previous
//
#include <hip/hip_runtime.h>
#include <cstdint>
#include <cstddef>

#define B_ 256
#define IW_ 3072
#define L_ 8
#define NN_ 7
#define FCIN_ 16384
#define OUTW_ 10
#define ICST 72            // ushorts per (row,col) cell: 64 ic + 8 pad
#define YPLANE (324 * ICST)   // 23328 us = 46.66 KB per buffer

typedef short short8 __attribute__((ext_vector_type(8)));
typedef float f32x4 __attribute__((ext_vector_type(4)));

__device__ __forceinline__ ushort f2bf(float x) {
    uint u = __float_as_uint(x);
    return (ushort)((u + 0x7fffu + ((u >> 16) & 1u)) >> 16);
}
__device__ __forceinline__ float bf2f(ushort b) { return __uint_as_float(((uint)b) << 16); }

// ---------- merged prep: [0,64) w1 repack | [64,1216) w2 repack | [1216,1472) mixture ----------
__global__ __launch_bounds__(256) void k_prep(const float* __restrict__ w1, ushort* __restrict__ w1fr,
                                              const float* __restrict__ w2, ushort* __restrict__ w2r,
                                              const float* __restrict__ x, const float* __restrict__ nw,
                                              const float* __restrict__ nb, float* __restrict__ mix) {
    int blk = blockIdx.x;
    if (blk < 64) {
        // conv1 weights -> frag-linear single RTN plane: [l8][mt4][lane64][j8]
        int i = blk * 256 + threadIdx.x;
        int j    = i & 7;
        int lane = (i >> 3) & 63;
        int mt   = (i >> 9) & 3;
        int l    = i >> 11;
        int fr = lane & 15, fq = lane >> 4;
        int oc = mt * 16 + fr;
        int k = fq * 8 + j;
        float w = (k < 27) ? w1[(size_t)(l * 64 + oc) * 27 + k] : 0.f;
        w1fr[i] = f2bf(w);
        return;
    }
    if (blk < 1216) {
        // conv2 weights -> [l8][icc2][tap9][mt4][lane64][j8], single RTN bf16 plane
        int i = (blk - 64) * 256 + threadIdx.x;
        int j     = i & 7;
        int lane  = (i >> 3) & 63;
        int mt    = (i >> 9) & 3;
        int tap   = (i >> 11) % 9;
        int icc   = (i / 18432) & 1;
        int l     = i / 36864;
        int fr = lane & 15, fq = lane >> 4;
        int oc = mt * 16 + fr;
        int ic = icc * 32 + fq * 8 + j;
        float w = w2[(((size_t)l * 64 + oc) * 64 + ic) * 9 + tap];
        w2r[i] = f2bf(w);
        return;
    }
    // mixture
    __shared__ float red[4 * NN_];
    __shared__ float bes[NN_];
    int b = blk - 1216, tid = threadIdx.x;
    const float* xb = x + (size_t)b * IW_;
    float p[NN_];
#pragma unroll
    for (int n = 0; n < NN_; ++n) p[n] = 0.f;
    for (int i = tid; i < IW_; i += 256) {
        float xv = xb[i];
#pragma unroll
        for (int n = 0; n < NN_; ++n) p[n] = fmaf(xv, nw[n * IW_ + i], p[n]);
    }
#pragma unroll
    for (int n = 0; n < NN_; ++n) {
        float v = p[n];
        for (int off = 32; off > 0; off >>= 1) v += __shfl_xor(v, off);
        if ((tid & 63) == 0) red[(tid >> 6) * NN_ + n] = v;
    }
    __syncthreads();
    if (tid < NN_) {
        float s = red[tid] + red[NN_ + tid] + red[2 * NN_ + tid] + red[3 * NN_ + tid] + nb[tid];
        bes[tid] = 1.f / (1.f + expf(-s));
    }
    __syncthreads();
    if (tid < L_) {
        int leaf = tid;
        float b0 = bes[0];
        float t0 = ((leaf >> 2) & 1) ? b0 : 1.f - b0;
        float b1v = bes[1 + ((leaf >> 2) & 1)];
        float t1 = ((leaf >> 1) & 1) ? b1v : 1.f - b1v;
        float b2v = bes[3 + ((leaf >> 1) & 3)];
        float t2 = (leaf & 1) ? b2v : 1.f - b2v;
        mix[b * L_ + leaf] = t0 * t1 * t2;
    }
}

// ---------- fully-fused conv1/conv2/fc: 1024 thr, full-leaf dbuf steps, fc from LDS ----------
// block = sample (grid 256 = 1/CU), 16 waves = 4 waves/SIMD. 8 leaf-steps:
//   conv1(l+1) -> ybuf[(l+1)&1]  ||  conv2(l) <- ybuf[l&1] (A-frags from global/L1) -> barrier.
// Epilogue: oacc -> LDS out1 tile (64KB) -> fc reduce vs ORIGINAL-layout fcw, k-loop
// NOT unrolled (R21's full unroll software-pipelined 160 loads -> spills, 107MB scratch).
__global__ __launch_bounds__(1024, 1) void k_fused(const float* __restrict__ x,
                                                   const ushort* __restrict__ w1fr,
                                                   const float* __restrict__ cb1,
                                                   const ushort* __restrict__ w2r,
                                                   const float* __restrict__ cb2, const float* __restrict__ mixw,
                                                   const float* __restrict__ fcw, const float* __restrict__ fcb,
                                                   float* __restrict__ out) {
    __shared__ __align__(16) ushort smem[2 * YPLANE];   // ybuf0 | ybuf1 = 93.3 KB
    float* xpad = (float*)smem;                          // prologue-only alias (13.9 KB)

    int tid = threadIdx.x;
    int b = blockIdx.x;
    int lane = tid & 63, wid = tid >> 6;                 // wid 0..15
    int fr = lane & 15, fq = lane >> 4;
    int mt = wid >> 2, ng = wid & 3;                     // conv2: mtile mt, rows {4ng..4ng+3}

    // ---- prologue: xpad zero + fill ----
    for (int i = tid; i < 3 * 34 * 34; i += 1024) xpad[i] = 0.f;
    __syncthreads();
    for (int i = tid; i < 3072; i += 1024) {
        int ch = i >> 10, rr = (i >> 5) & 31, cc = i & 31;
        xpad[(ch * 34 + rr + 1) * 34 + cc + 1] = x[(size_t)b * IW_ + i];
    }
    __syncthreads();

    // ---- leaf-invariant conv1 im2col B-frags: wave owns pooled row wid ----
    short8 Bh[4];
#pragma unroll
    for (int i = 0; i < 4; ++i) {
        int subrow = i >> 1;
        int parity = i & 1;
        int prow = wid * 2 + subrow;          // 0..31
        int pcol = 2 * fr + parity;           // 0..31
#pragma unroll
        for (int j = 0; j < 8; ++j) {
            int k = fq * 8 + j;               // k = ic*9 + tap
            float xv = 0.f;
            if (k < 27) {
                int ic = k / 9;
                int tap = k - ic * 9;
                int dr = tap / 3, dc = tap - dr * 3;
                xv = xpad[(ic * 34 + prow + dr) * 34 + (pcol + dc)];
            }
            Bh[i][j] = (short)f2bf(xv);
        }
    }
    __syncthreads();
    {   // zero BOTH y planes (borders stay zero forever)
        uint4 z; z.x = z.y = z.z = z.w = 0u;
        for (int i = tid; i < (2 * YPLANE) / 8; i += 1024) ((uint4*)smem)[i] = z;
    }
    __syncthreads();

    f32x4 acc[4], oacc[4];
#pragma unroll
    for (int rl = 0; rl < 4; ++rl) { acc[rl] = (f32x4)0.f; oacc[rl] = (f32x4)0.f; }

    // conv1(l): all 64 chans of leaf l for pooled row wid -> ybuf[l&1]
    auto CONV1 = [&](int l) {
        ushort* yt = smem + (size_t)(l & 1) * YPLANE;
#pragma unroll
        for (int mtg = 0; mtg < 4; ++mtg) {
            short8 ah = *(const short8*)(w1fr + ((size_t)(l * 4 + mtg) * 64 + lane) * 8);
            f32x4 a1[4];
#pragma unroll
            for (int i = 0; i < 4; ++i) {
                f32x4 t = (f32x4)0.f;
                t = __builtin_amdgcn_mfma_f32_16x16x32_bf16(ah, Bh[i], t, 0, 0, 0);
                a1[i] = t;
            }
            float4 bias4 = *(const float4*)(cb1 + l * 64 + mtg * 16 + fq * 4);
            float bb[4] = {bias4.x, bias4.y, bias4.z, bias4.w};
            ushort hb[4];
#pragma unroll
            for (int j2 = 0; j2 < 4; ++j2) {
                float m0 = fmaxf(fmaxf(a1[0][j2], a1[1][j2]), fmaxf(a1[2][j2], a1[3][j2]));
                float v = fmaxf(m0 + bb[j2], 0.f);
                hb[j2] = f2bf(v);
            }
            int off = ((wid + 1) * 18 + (fr + 1)) * ICST + mtg * 16 + fq * 4;
            uint2 H;
            H.x = (uint)hb[0] | ((uint)hb[1] << 16);
            H.y = (uint)hb[2] | ((uint)hb[3] << 16);
            *(uint2*)&yt[off] = H;
        }
    };

    // conv2(l): reads ybuf[l&1], full K=64 (2 icc); A-frags from global (L1/L2-broadcast)
    auto CONV2 = [&](int l) {
        const ushort* yt = smem + (size_t)(l & 1) * YPLANE;
#pragma unroll
        for (int dc = 0; dc < 3; ++dc) {
#pragma unroll
            for (int icc = 0; icc < 2; ++icc) {
                const ushort* wbase = w2r + (size_t)(l * 2 + icc) * 18432;
                short8 Ah[3];
#pragma unroll
                for (int dr = 0; dr < 3; ++dr) {
                    int tap = dr * 3 + dc;
                    Ah[dr] = *(const short8*)(wbase + ((size_t)(tap * 4 + mt) * 64 + lane) * 8);
                }
#pragma unroll
                for (int rr = 0; rr < 6; ++rr) {
                    int off = ((4 * ng + rr) * 18 + (fr + dc)) * ICST + icc * 32 + fq * 8;
                    short8 bh = *(const short8*)(yt + off);
#pragma unroll
                    for (int dr = 0; dr < 3; ++dr) {
                        int rl = rr - dr;
                        if (rl >= 0 && rl < 4) {
                            acc[rl] = __builtin_amdgcn_mfma_f32_16x16x32_bf16(Ah[dr], bh, acc[rl], 0, 0, 0);
                        }
                    }
                }
            }
        }
        // leaf epilogue: bias + relu + mixture accumulate
        float mx = mixw[(size_t)b * 8 + l];
#pragma unroll
        for (int j = 0; j < 4; ++j) {
            float bias = cb2[l * 64 + mt * 16 + fq * 4 + j];
#pragma unroll
            for (int rl = 0; rl < 4; ++rl) {
                float v = fmaxf(acc[rl][j] + bias, 0.f);
                oacc[rl][j] = fmaf(mx, v, oacc[rl][j]);
                acc[rl][j] = 0.f;
            }
        }
    };

    // ---- software pipeline: conv1(l+1) || conv2(l), one barrier per leaf ----
    CONV1(0);
    __syncthreads();
    for (int l = 0; l < 8; ++l) {
        if (l < 7) CONV1(l + 1);
        CONV2(l);
        __syncthreads();
    }

    // ---- fc epilogue: oacc -> LDS out1 tile, then coalesced fcw reduce (NO unroll) ----
    float* ldsOut = (float*)smem;          // 16384 floats = 64 KB (fits in 93.3)
    float* sred   = (float*)smem + FCIN_;  // 160 floats after the tile
#pragma unroll
    for (int rl = 0; rl < 4; ++rl)
#pragma unroll
        for (int j = 0; j < 4; ++j) {
            int oc = mt * 16 + fq * 4 + j;
            int pos = (4 * ng + rl) * 16 + fr;
            ldsOut[oc * 256 + pos] = oacc[rl][j];
        }
    __syncthreads();
    float pj[OUTW_];
#pragma unroll
    for (int j = 0; j < OUTW_; ++j) pj[j] = 0.f;
#pragma unroll 1
    for (int k = 0; k < 16; ++k) {          // unroll 1: R21's full unroll spilled (107MB scratch)
        float yv = ldsOut[k * 1024 + tid];
        const float* fp = fcw + k * 1024 + tid;
#pragma unroll
        for (int jj = 0; jj < OUTW_; ++jj)
            pj[jj] = fmaf(yv, fp[(size_t)jj * FCIN_], pj[jj]);
    }
#pragma unroll
    for (int jj = 0; jj < OUTW_; ++jj) {
        float v = pj[jj];
        for (int off = 32; off > 0; off >>= 1) v += __shfl_xor(v, off);
        if (lane == 0) sred[wid * OUTW_ + jj] = v;
    }
    __syncthreads();
    if (tid < OUTW_) {
        float s = fcb[tid];
#pragma unroll
        for (int w = 0; w < 16; ++w) s += sred[w * OUTW_ + tid];
        out[(size_t)b * OUTW_ + tid] = s;
    }
}

extern "C" void kernel_launch(void* const* d_in, const int* in_sizes, int n_in,
                              void* d_out, int out_size, void* d_ws, size_t ws_size,
                              hipStream_t stream) {
    const float* x   = (const float*)d_in[0];
    const float* nw  = (const float*)d_in[1];
    const float* nb  = (const float*)d_in[2];
    const float* w1  = (const float*)d_in[3];
    const float* cb1 = (const float*)d_in[4];
    const float* w2  = (const float*)d_in[5];
    const float* cb2 = (const float*)d_in[6];
    const float* fcw = (const float*)d_in[7];
    const float* fcb = (const float*)d_in[8];
    float* out = (float*)d_out;

    float*  ws   = (float*)d_ws;
    float*  mix  = ws;                        // 2048 f
    ushort* w1fr = (ushort*)(mix + 2048);     // 16384 us (single RTN plane)
    ushort* w2r  = w1fr + 16384;              // 294912 us ([l][icc][tap][mt][lane][j8] single plane)
    // fixed bytes: 2048*4 + 16384*2 + 294912*2 = 630784 (< ws_size)

    k_prep<<<1472, 256, 0, stream>>>(w1, w1fr, w2, w2r, x, nw, nb, mix);
    k_fused<<<B_, 1024, 0, stream>>>(x, w1fr, cb1, w2r, cb2, mix, fcw, fcb, out);
}